// Round 7
// baseline (2287.139 us; speedup 1.0000x reference)
//
#include <hip/hip_runtime.h>
#include <stdint.h>

#define BATCH 32
#define NV 32768
#define NF 65536
#define PCOUNT (NV*3)

// Output layout (floats, concatenated in reference return order):
// input_ids      (32, 589826)      @ 0
// attention_mask (32, 589826)      @ 18874432
// codes          (32, 65536, 3, 3) @ 37748864
// dq             (32, 65536, 3, 3) @ 56623232
// sorted_faces   (32, 65536, 3)    @ 75497600

__device__ __forceinline__ unsigned fenc(float f){
  unsigned u = __float_as_uint(f);
  return (u & 0x80000000u) ? ~u : (u | 0x80000000u);
}
__device__ __forceinline__ float fdec(unsigned e){
  unsigned u = (e & 0x80000000u) ? (e & 0x7FFFFFFFu) : ~e;
  return __uint_as_float(u);
}

__global__ void kminmax(const float* __restrict__ vert, float* __restrict__ center,
                        unsigned* __restrict__ longestBits){
  int p = blockIdx.x*256 + threadIdx.x;   // 0..98303
  float mn = 3.4e38f, mx = -3.4e38f;
  #pragma unroll
  for (int b = 0; b < BATCH; ++b) {
    float v = vert[(size_t)b*PCOUNT + p];
    mn = fminf(mn, v); mx = fmaxf(mx, v);
  }
  center[p] = __fadd_rn(mn, mx) * 0.5f;
  float r = __fsub_rn(mx, mn);             // CR sub, >= 0
  for (int off = 32; off > 0; off >>= 1) r = fmaxf(r, __shfl_down(r, off, 64));
  if ((threadIdx.x & 63) == 0) atomicMax(longestBits, __float_as_uint(r));
}

// Vertex records {fenc(x), fenc(y), fenc(z), idx}.
// PROBE: division as multiply-by-CR-reciprocal (x * (1/L)) instead of CR division.
__global__ void kvkeys(const float* __restrict__ vert, const float* __restrict__ center,
                       const unsigned* __restrict__ longestBits, uint4* __restrict__ S){
  int id = blockIdx.x*256 + threadIdx.x;   // 0..BATCH*NV-1
  int b = id >> 15, i = id & (NV-1);
  float L = __uint_as_float(*longestBits);
  float rl = __fdiv_rn(1.0f, L);           // CR reciprocal
  size_t vb = (size_t)b*PCOUNT + (size_t)i*3;
  float nx = __fsub_rn(vert[vb+0], center[i*3+0]);
  float ny = __fsub_rn(vert[vb+1], center[i*3+1]);
  float nz = __fsub_rn(vert[vb+2], center[i*3+2]);
  float x = __fmul_rn(nx, rl);
  float y = __fmul_rn(ny, rl);
  float z = __fmul_rn(nz, rl);
  uint4 s; s.x = fenc(x); s.y = fenc(y); s.z = fenc(z); s.w = (unsigned)i;
  S[id] = s;
}

// ---------------- Stable LSD radix, one workgroup per batch -----------------
#define RT 256
#define RBINS 64
#define HPITCH 257

__global__ __launch_bounds__(RT) void radix_vert(uint4* __restrict__ A, uint4* __restrict__ B){
  __shared__ unsigned short hist[RBINS*HPITCH];
  __shared__ unsigned segsum[RBINS][4];
  __shared__ unsigned starts[RBINS];
  const int C = NV / RT;
  int t = threadIdx.x;
  uint4* src = A + (size_t)blockIdx.x * NV;
  uint4* dst = B + (size_t)blockIdx.x * NV;
  for (int p = 0; p < 18; ++p){
    int w = p / 6, sh = (p % 6) * 6;
    unsigned mk = (sh == 30) ? 3u : 63u;
    for (int k = t; k < RBINS*HPITCH; k += RT) hist[k] = 0;
    __syncthreads();
    for (int e = 0; e < C; ++e){
      uint4 r = src[t*C + e];
      unsigned key = (w==0) ? r.x : (w==1) ? r.y : r.z;
      hist[((key>>sh)&mk)*HPITCH + t]++;
    }
    __syncthreads();
    int d = t >> 2, seg = t & 3;
    unsigned s0 = 0;
    for (int c = seg*64; c < seg*64+64; ++c) s0 += hist[d*HPITCH + c];
    segsum[d][seg] = s0;
    __syncthreads();
    if (t == 0){
      unsigned acc = 0;
      for (int dd = 0; dd < RBINS; ++dd){
        unsigned tt = segsum[dd][0]+segsum[dd][1]+segsum[dd][2]+segsum[dd][3];
        starts[dd] = acc; acc += tt;
      }
    }
    __syncthreads();
    unsigned base = starts[d];
    for (int q = 0; q < seg; ++q) base += segsum[d][q];
    for (int c = seg*64; c < seg*64+64; ++c){
      unsigned cc = hist[d*HPITCH + c];
      hist[d*HPITCH + c] = (unsigned short)base;
      base += cc;
    }
    __syncthreads();
    for (int e = 0; e < C; ++e){
      uint4 r = src[t*C + e];
      unsigned key = (w==0) ? r.x : (w==1) ? r.y : r.z;
      unsigned dd = (key>>sh)&mk;
      unsigned pos = hist[dd*HPITCH + t];
      hist[dd*HPITCH + t] = (unsigned short)(pos + 1);
      dst[pos] = r;
    }
    __syncthreads();
    uint4* tmp = src; src = dst; dst = tmp;
  }
}

__global__ __launch_bounds__(RT) void radix_face(uint2* __restrict__ A, uint2* __restrict__ B){
  __shared__ unsigned short hist[RBINS*HPITCH];
  __shared__ unsigned segsum[RBINS][4];
  __shared__ unsigned starts[RBINS];
  const int C = NF / RT;
  int t = threadIdx.x;
  uint2* src = B + (size_t)blockIdx.x * NF;
  uint2* dst = A + (size_t)blockIdx.x * NF;
  for (int p = 0; p < 9; ++p){
    int w = p / 3, k3 = p % 3;
    int sh = (w == 2) ? (15 + k3*6) : (k3*6);
    unsigned mk = (k3 == 2) ? 7u : 63u;
    bool uselo = (w == 0);
    for (int k = t; k < RBINS*HPITCH; k += RT) hist[k] = 0;
    __syncthreads();
    for (int e = 0; e < C; ++e){
      uint2 r = src[t*C + e];
      unsigned key = uselo ? r.x : r.y;
      hist[((key>>sh)&mk)*HPITCH + t]++;
    }
    __syncthreads();
    int d = t >> 2, seg = t & 3;
    unsigned s0 = 0;
    for (int c = seg*64; c < seg*64+64; ++c) s0 += hist[d*HPITCH + c];
    segsum[d][seg] = s0;
    __syncthreads();
    if (t == 0){
      unsigned acc = 0;
      for (int dd = 0; dd < RBINS; ++dd){
        unsigned tt = segsum[dd][0]+segsum[dd][1]+segsum[dd][2]+segsum[dd][3];
        starts[dd] = acc; acc += tt;
      }
    }
    __syncthreads();
    unsigned base = starts[d];
    for (int q = 0; q < seg; ++q) base += segsum[d][q];
    for (int c = seg*64; c < seg*64+64; ++c){
      unsigned cc = hist[d*HPITCH + c];
      hist[d*HPITCH + c] = (unsigned short)base;
      base += cc;
    }
    __syncthreads();
    for (int e = 0; e < C; ++e){
      uint2 r = src[t*C + e];
      unsigned key = uselo ? r.x : r.y;
      unsigned dd = (key>>sh)&mk;
      unsigned pos = hist[dd*HPITCH + t];
      hist[dd*HPITCH + t] = (unsigned short)(pos + 1);
      dst[pos] = r;
    }
    __syncthreads();
    uint2* tmp = src; src = dst; dst = tmp;
  }
}
// ---------------------------------------------------------------------------

__global__ void kinv(const uint4* __restrict__ S, int* __restrict__ inv){
  int id = blockIdx.x*256 + threadIdx.x;
  int b = id >> 15, j = id & (NV-1);
  inv[(b<<15) + (int)S[id].w] = j;
}

__global__ void kfacesB(const int* __restrict__ faces, const uint4* __restrict__ S,
                        float* __restrict__ out){
  #pragma clang fp contract(off)
  int id = blockIdx.x*256 + threadIdx.x;
  int b = id >> 16, f = id & (NF-1);
  size_t fb = (size_t)id*3;
  int f0 = faces[fb+0], f1 = faces[fb+1], f2 = faces[fb+2];
  bool mask = (f0 != -1) & (f1 != -1) & (f2 != -1);

  float* ids   = out +            (size_t)b*589826 + 1 + (size_t)f*9;
  float* attn  = out + 18874432 + (size_t)b*589826 + 1 + (size_t)f*9;
  float* codes = out + 37748864 + (size_t)id*9;
  float* dq    = out + 56623232 + (size_t)id*9;
  float amv = mask ? 1.0f : 0.0f;
  int fv[3] = {mask ? f0 : 0, mask ? f1 : 0, mask ? f2 : 0};
  #pragma unroll
  for (int k = 0; k < 3; ++k){
    uint4 s = S[(b<<15) + fv[k]];
    float c[3]; c[0] = fdec(s.x); c[1] = fdec(s.y); c[2] = fdec(s.z);
    #pragma unroll
    for (int cc = 0; cc < 3; ++cc){
      float t = ((c[cc] + 1.0f) * 0.5f) * 128.0f - 0.5f;
      float rq = rintf(t);
      int qi = (int)rq;
      qi = qi < 0 ? 0 : (qi > 127 ? 127 : qi);
      int code = mask ? qi : -1;
      dq[k*3+cc]    = (float)qi;
      codes[k*3+cc] = (float)code;
      ids[k*3+cc]   = (float)code;
      attn[k*3+cc]  = amv;
    }
  }
  if (f == 0){
    out[(size_t)b*589826]                       = -1.0f;
    out[(size_t)b*589826 + 589825]              = -1.0f;
    out[18874432 + (size_t)b*589826]            = -1.0f;
    out[18874432 + (size_t)b*589826 + 589825]   = -1.0f;
  }
}

__global__ void kfacesFK(const int* __restrict__ faces, const int* __restrict__ inv,
                         uint2* __restrict__ FK){
  int id = blockIdx.x*256 + threadIdx.x;
  int b = id >> 16, f = id & (NF-1);
  size_t fb = (size_t)id*3;
  int f0 = faces[fb+0], f1 = faces[fb+1], f2 = faces[fb+2];
  unsigned r0 = (unsigned)inv[(b<<15) + (f0 & (NV-1))];
  unsigned r1 = (unsigned)inv[(b<<15) + (f1 & (NV-1))];
  unsigned r2 = (unsigned)inv[(b<<15) + (f2 & (NV-1))];
  uint2 r; r.x = r0 | ((unsigned)f << 15); r.y = r1 | (r2 << 15);
  FK[id] = r;
}

__global__ void ksfout(const uint2* __restrict__ FK, float* __restrict__ out){
  int id = blockIdx.x*256 + threadIdx.x;
  uint2 r = FK[id];
  float* o = out + 75497600 + (size_t)id*3;
  o[0] = (float)(r.x & 0x7FFFu);
  o[1] = (float)(r.y & 0x7FFFu);
  o[2] = (float)((r.y >> 15) & 0x7FFFu);
}

extern "C" void kernel_launch(void* const* d_in, const int* in_sizes, int n_in,
                              void* d_out, int out_size, void* d_ws, size_t ws_size,
                              hipStream_t stream){
  const float* vert  = (const float*)d_in[0];
  const int*   faces = (const int*)d_in[1];
  float* out = (float*)d_out;

  uint4*    S           = (uint4*)d_ws;                         // 16 MiB
  uint4*    S2          = (uint4*)((char*)d_ws + 16777216);     // 16 MiB
  uint2*    FK0         = (uint2*)((char*)d_ws + 16777216);     // reuses S2
  uint2*    FK1         = (uint2*)d_ws;                         // reuses S
  int*      inv         = (int*)((char*)d_ws + 33554432);       // 4 MiB
  float*    center      = (float*)((char*)d_ws + 37748736);     // 384 KiB
  unsigned* longestBits = (unsigned*)((char*)d_ws + 38141952);  // 4 B

  hipMemsetAsync(longestBits, 0, 4, stream);
  kminmax<<<PCOUNT/256, 256, 0, stream>>>(vert, center, longestBits);
  kvkeys<<<(BATCH*NV)/256, 256, 0, stream>>>(vert, center, longestBits, S);
  radix_vert<<<BATCH, RT, 0, stream>>>(S, S2);
  kinv<<<(BATCH*NV)/256, 256, 0, stream>>>(S, inv);
  kfacesB<<<(BATCH*NF)/256, 256, 0, stream>>>(faces, S, out);
  kfacesFK<<<(BATCH*NF)/256, 256, 0, stream>>>(faces, inv, FK1);
  radix_face<<<BATCH, RT, 0, stream>>>(FK0, FK1);
  ksfout<<<(BATCH*NF)/256, 256, 0, stream>>>(FK0, out);
}

// Round 8
// 1013.314 us; speedup vs baseline: 2.2571x; 2.2571x over previous
//
#include <hip/hip_runtime.h>
#include <stdint.h>

#define BATCH 32
#define NV 32768
#define NF 65536
#define PCOUNT (NV*3)

// Output layout (floats, concatenated in reference return order):
// input_ids      (32, 589826)      @ 0
// attention_mask (32, 589826)      @ 18874432
// codes          (32, 65536, 3, 3) @ 37748864
// dq             (32, 65536, 3, 3) @ 56623232
// sorted_faces   (32, 65536, 3)    @ 75497600
//
// Workspace: S @0 (16MB) | S2/FKa @16MB (16MB) | inv @32MB (4MB) | center | lbits
// FKb reuses S region (dead after kfacesB).

__device__ __forceinline__ unsigned fenc(float f){
  unsigned u = __float_as_uint(f);
  return (u & 0x80000000u) ? ~u : (u | 0x80000000u);
}
__device__ __forceinline__ float fdec(unsigned e){
  unsigned u = (e & 0x80000000u) ? (e & 0x7FFFFFFFu) : ~e;
  return __uint_as_float(u);
}

__global__ void kminmax(const float* __restrict__ vert, float* __restrict__ center,
                        unsigned* __restrict__ longestBits){
  int p = blockIdx.x*256 + threadIdx.x;   // 0..98303
  float mn = 3.4e38f, mx = -3.4e38f;
  #pragma unroll
  for (int b = 0; b < BATCH; ++b) {
    float v = vert[(size_t)b*PCOUNT + p];
    mn = fminf(mn, v); mx = fmaxf(mx, v);
  }
  center[p] = __fadd_rn(mn, mx) * 0.5f;
  float r = __fsub_rn(mx, mn);
  for (int off = 32; off > 0; off >>= 1) r = fmaxf(r, __shfl_down(r, off, 64));
  if ((threadIdx.x & 63) == 0) atomicMax(longestBits, __float_as_uint(r));
}

// Vertex records {fenc(z), fenc(y), fenc(x), idx} — compared lexicographically.
// Normalization: x * (1/L) with CR reciprocal — matches the generator (round 7).
__global__ void kvkeys(const float* __restrict__ vert, const float* __restrict__ center,
                       const unsigned* __restrict__ longestBits, uint4* __restrict__ S){
  int id = blockIdx.x*256 + threadIdx.x;   // 0..BATCH*NV-1
  int b = id >> 15, i = id & (NV-1);
  float L = __uint_as_float(*longestBits);
  float rl = __fdiv_rn(1.0f, L);
  size_t vb = (size_t)b*PCOUNT + (size_t)i*3;
  float nx = __fsub_rn(vert[vb+0], center[i*3+0]);
  float ny = __fsub_rn(vert[vb+1], center[i*3+1]);
  float nz = __fsub_rn(vert[vb+2], center[i*3+2]);
  float x = __fmul_rn(nx, rl);
  float y = __fmul_rn(ny, rl);
  float z = __fmul_rn(nz, rl);
  uint4 s; s.x = fenc(z); s.y = fenc(y); s.z = fenc(x); s.w = (unsigned)i;
  S[id] = s;
}

__device__ __forceinline__ bool less4(uint4 a, uint4 b){
  if (a.x != b.x) return a.x < b.x;
  if (a.y != b.y) return a.y < b.y;
  if (a.z != b.z) return a.z < b.z;
  return a.w < b.w;                        // idx: unique -> total order
}
// Face record: lo=(r0<<15)|f, hi=(r2<<15)|r1 -> compare hi then lo == (r2,r1,r0,f).
__device__ __forceinline__ bool less2(uint2 a, uint2 b){
  if (a.y != b.y) return a.y < b.y;
  return a.x < b.x;                        // f: unique -> total order
}

// ---------------- LDS bitonic local sorts -----------------------------------
#define VT 2048   // vertex tile
#define FT 4096   // face tile

__global__ __launch_bounds__(256) void klocalv(uint4* __restrict__ S){
  __shared__ uint4 sh[VT];
  uint4* base = S + (size_t)blockIdx.x * VT;
  for (int i = threadIdx.x; i < VT; i += 256) sh[i] = base[i];
  __syncthreads();
  for (int k = 2; k <= VT; k <<= 1){
    for (int j = k >> 1; j > 0; j >>= 1){
      for (int t = threadIdx.x; t < VT/2; t += 256){
        int i = ((t & ~(j-1)) << 1) | (t & (j-1));
        int l = i | j;
        uint4 A = sh[i], Bv = sh[l];
        bool up = ((i & k) == 0);
        bool sw = up ? less4(Bv, A) : less4(A, Bv);
        if (sw){ sh[i] = Bv; sh[l] = A; }
      }
      __syncthreads();
    }
  }
  for (int i = threadIdx.x; i < VT; i += 256) base[i] = sh[i];
}

__global__ __launch_bounds__(256) void klocalf(uint2* __restrict__ F){
  __shared__ uint2 sh[FT];
  uint2* base = F + (size_t)blockIdx.x * FT;
  for (int i = threadIdx.x; i < FT; i += 256) sh[i] = base[i];
  __syncthreads();
  for (int k = 2; k <= FT; k <<= 1){
    for (int j = k >> 1; j > 0; j >>= 1){
      for (int t = threadIdx.x; t < FT/2; t += 256){
        int i = ((t & ~(j-1)) << 1) | (t & (j-1));
        int l = i | j;
        uint2 A = sh[i], Bv = sh[l];
        bool up = ((i & k) == 0);
        bool sw = up ? less2(Bv, A) : less2(A, Bv);
        if (sw){ sh[i] = Bv; sh[l] = A; }
      }
      __syncthreads();
    }
  }
  for (int i = threadIdx.x; i < FT; i += 256) base[i] = sh[i];
}

// ---------------- Merge-path merge rounds ------------------------------------
// Vertex: batch = 32768 recs, output chunk 2048/WG (16 chunks/batch), 8 outs/thread.
__global__ __launch_bounds__(256) void kmergev(const uint4* __restrict__ src,
                                               uint4* __restrict__ dst, int L){
  int gid = blockIdx.x;
  int b = gid >> 4, c = gid & 15;
  const uint4* base = src + ((size_t)b << 15);
  uint4* obase = dst + ((size_t)b << 15);
  int co = c * 2048;
  int pair = co / (2*L);
  int ko = co - pair*2*L;
  const uint4* A = base + (size_t)pair*2*L;
  const uint4* B = A + L;
  uint4* O = obase + (size_t)pair*2*L;
  int k0 = ko + threadIdx.x * 8;
  int lo = k0 - L; if (lo < 0) lo = 0;
  int hi = k0 < L ? k0 : L;
  while (lo < hi){
    int mid = (lo + hi) >> 1;
    if (less4(A[mid], B[k0-1-mid])) lo = mid + 1; else hi = mid;
  }
  int i = lo, j = k0 - lo;
  #pragma unroll
  for (int e = 0; e < 8; ++e){
    bool takeA = (j >= L) || (i < L && less4(A[i], B[j]));
    uint4 v = takeA ? A[i] : B[j];
    if (takeA) ++i; else ++j;
    O[k0 + e] = v;
  }
}

// Face: batch = 65536 recs, output chunk 2048/WG (32 chunks/batch), 8 outs/thread.
__global__ __launch_bounds__(256) void kmergef(const uint2* __restrict__ src,
                                               uint2* __restrict__ dst, int L){
  int gid = blockIdx.x;
  int b = gid >> 5, c = gid & 31;
  const uint2* base = src + ((size_t)b << 16);
  uint2* obase = dst + ((size_t)b << 16);
  int co = c * 2048;
  int pair = co / (2*L);
  int ko = co - pair*2*L;
  const uint2* A = base + (size_t)pair*2*L;
  const uint2* B = A + L;
  uint2* O = obase + (size_t)pair*2*L;
  int k0 = ko + threadIdx.x * 8;
  int lo = k0 - L; if (lo < 0) lo = 0;
  int hi = k0 < L ? k0 : L;
  while (lo < hi){
    int mid = (lo + hi) >> 1;
    if (less2(A[mid], B[k0-1-mid])) lo = mid + 1; else hi = mid;
  }
  int i = lo, j = k0 - lo;
  #pragma unroll
  for (int e = 0; e < 8; ++e){
    bool takeA = (j >= L) || (i < L && less2(A[i], B[j]));
    uint2 v = takeA ? A[i] : B[j];
    if (takeA) ++i; else ++j;
    O[k0 + e] = v;
  }
}
// -----------------------------------------------------------------------------

__global__ void kinv(const uint4* __restrict__ S, int* __restrict__ inv){
  int id = blockIdx.x*256 + threadIdx.x;
  int b = id >> 15, j = id & (NV-1);
  inv[(b<<15) + (int)S[id].w] = j;
}

__global__ void kfacesB(const int* __restrict__ faces, const uint4* __restrict__ S,
                        float* __restrict__ out){
  #pragma clang fp contract(off)
  int id = blockIdx.x*256 + threadIdx.x;
  int b = id >> 16, f = id & (NF-1);
  size_t fb = (size_t)id*3;
  int f0 = faces[fb+0], f1 = faces[fb+1], f2 = faces[fb+2];
  bool mask = (f0 != -1) & (f1 != -1) & (f2 != -1);

  float* ids   = out +            (size_t)b*589826 + 1 + (size_t)f*9;
  float* attn  = out + 18874432 + (size_t)b*589826 + 1 + (size_t)f*9;
  float* codes = out + 37748864 + (size_t)id*9;
  float* dq    = out + 56623232 + (size_t)id*9;
  float amv = mask ? 1.0f : 0.0f;
  int fv[3] = {mask ? f0 : 0, mask ? f1 : 0, mask ? f2 : 0};
  #pragma unroll
  for (int k = 0; k < 3; ++k){
    uint4 s = S[(b<<15) + fv[k]];
    float c[3]; c[0] = fdec(s.z); c[1] = fdec(s.y); c[2] = fdec(s.x); // (x,y,z)
    #pragma unroll
    for (int cc = 0; cc < 3; ++cc){
      float t = ((c[cc] + 1.0f) * 0.5f) * 128.0f - 0.5f;
      float rq = rintf(t);
      int qi = (int)rq;
      qi = qi < 0 ? 0 : (qi > 127 ? 127 : qi);
      int code = mask ? qi : -1;
      dq[k*3+cc]    = (float)qi;
      codes[k*3+cc] = (float)code;
      ids[k*3+cc]   = (float)code;
      attn[k*3+cc]  = amv;
    }
  }
  if (f == 0){
    out[(size_t)b*589826]                       = -1.0f;
    out[(size_t)b*589826 + 589825]              = -1.0f;
    out[18874432 + (size_t)b*589826]            = -1.0f;
    out[18874432 + (size_t)b*589826 + 589825]   = -1.0f;
  }
}

__global__ void kfacesFK(const int* __restrict__ faces, const int* __restrict__ inv,
                         uint2* __restrict__ FK){
  int id = blockIdx.x*256 + threadIdx.x;
  int b = id >> 16, f = id & (NF-1);
  size_t fb = (size_t)id*3;
  int f0 = faces[fb+0], f1 = faces[fb+1], f2 = faces[fb+2];
  unsigned r0 = (unsigned)inv[(b<<15) + (f0 & (NV-1))];
  unsigned r1 = (unsigned)inv[(b<<15) + (f1 & (NV-1))];
  unsigned r2 = (unsigned)inv[(b<<15) + (f2 & (NV-1))];
  uint2 r; r.x = (r0 << 15) | (unsigned)f; r.y = (r2 << 15) | r1;
  FK[id] = r;
}

__global__ void ksfout(const uint2* __restrict__ FK, float* __restrict__ out){
  int id = blockIdx.x*256 + threadIdx.x;
  uint2 r = FK[id];
  float* o = out + 75497600 + (size_t)id*3;
  o[0] = (float)(r.x >> 15);              // r0
  o[1] = (float)(r.y & 0x7FFFu);          // r1
  o[2] = (float)(r.y >> 15);              // r2
}

extern "C" void kernel_launch(void* const* d_in, const int* in_sizes, int n_in,
                              void* d_out, int out_size, void* d_ws, size_t ws_size,
                              hipStream_t stream){
  const float* vert  = (const float*)d_in[0];
  const int*   faces = (const int*)d_in[1];
  float* out = (float*)d_out;

  uint4*    S           = (uint4*)d_ws;                         // 16 MiB
  uint4*    S2          = (uint4*)((char*)d_ws + 16777216);     // 16 MiB
  uint2*    FKa         = (uint2*)((char*)d_ws + 16777216);     // reuses S2
  uint2*    FKb         = (uint2*)d_ws;                         // reuses S
  int*      inv         = (int*)((char*)d_ws + 33554432);       // 4 MiB
  float*    center      = (float*)((char*)d_ws + 37748736);     // 384 KiB
  unsigned* longestBits = (unsigned*)((char*)d_ws + 38141952);  // 4 B

  hipMemsetAsync(longestBits, 0, 4, stream);
  kminmax<<<PCOUNT/256, 256, 0, stream>>>(vert, center, longestBits);
  kvkeys<<<(BATCH*NV)/256, 256, 0, stream>>>(vert, center, longestBits, S);

  // vertex sort: local 2048-tiles, then 4 merge rounds (ends in S)
  klocalv<<<BATCH*(NV/VT), 256, 0, stream>>>(S);
  kmergev<<<BATCH*16, 256, 0, stream>>>(S,  S2, 2048);
  kmergev<<<BATCH*16, 256, 0, stream>>>(S2, S,  4096);
  kmergev<<<BATCH*16, 256, 0, stream>>>(S,  S2, 8192);
  kmergev<<<BATCH*16, 256, 0, stream>>>(S2, S,  16384);

  kinv<<<(BATCH*NV)/256, 256, 0, stream>>>(S, inv);
  kfacesB<<<(BATCH*NF)/256, 256, 0, stream>>>(faces, S, out);   // S dead after
  kfacesFK<<<(BATCH*NF)/256, 256, 0, stream>>>(faces, inv, FKa);

  // face sort: local 4096-tiles, then 4 merge rounds (ends in FKa)
  klocalf<<<BATCH*(NF/FT), 256, 0, stream>>>(FKa);
  kmergef<<<BATCH*32, 256, 0, stream>>>(FKa, FKb, 4096);
  kmergef<<<BATCH*32, 256, 0, stream>>>(FKb, FKa, 8192);
  kmergef<<<BATCH*32, 256, 0, stream>>>(FKa, FKb, 16384);
  kmergef<<<BATCH*32, 256, 0, stream>>>(FKb, FKa, 32768);

  ksfout<<<(BATCH*NF)/256, 256, 0, stream>>>(FKa, out);
}